// Round 3
// baseline (166.749 us; speedup 1.0000x reference)
//
#include <hip/hip_runtime.h>

#define IMW 512
#define NP 4096

#define GATHER_BLOCKS 128
#define DIST_BLOCKS 2048               // 8 batches x 16 i-blocks x 16 j-chunks (256x256 tiles)
#define TOTAL_BLOCKS (GATHER_BLOCKS + DIST_BLOCKS)

// Gaussian kernel, sigma = 0.3*((11-1)*0.5 - 1) + 0.8 = 2.0, normalized (f64-accurate, rounded to f32)
__device__ constexpr float KW[11] = {
    0.00881223f, 0.02714359f, 0.06511407f, 0.12164908f, 0.17699836f,
    0.20056542f, 0.17699836f, 0.12164908f, 0.06511407f, 0.02714359f, 0.00881223f};

// reflect map: valid for r in [-5, 517]; matches both the blur pad and the intensity pad (512->510, 513->509)
__device__ __forceinline__ int refl(int r) {
    r = r < 0 ? -r : r;
    return r > 511 ? 1022 - r : r;
}

// Single fused kernel:
//   blocks [0,128):   intensity gather with inline 2D separable blur from raw img (no blur pass needed)
//   blocks [128,...): dist-push partial sums over 256x256 point tiles
// Last-arriving block folds the two accumulators into the scalar output.
__global__ __launch_bounds__(256)
void fused_loss(const float* __restrict__ trace, const float* __restrict__ img,
                float* __restrict__ accs, unsigned* __restrict__ cnt, float* __restrict__ out) {
    const int tid = threadIdx.x;
    const int bx = blockIdx.x;
    __shared__ float2 pj[256];
    __shared__ float red[4];
    float local;
    int acc_idx;

    if (bx < GATHER_BLOCKS) {
        // ---- intensity gather (+ full 2D blur inline) ----
        const int b = bx >> 4;
        const int p = (bx & 15) * 256 + tid;
        const float2 t2 = ((const float2*)trace)[b * NP + p];
        const float idx0 = t2.x * 512.f, idx1 = t2.y * 512.f;
        const float i0f = floorf(idx0 + 0.5f), j0f = floorf(idx1 + 0.5f);
        const float wi = idx0 - i0f, wj = idx1 - j0f;
        const int i0 = (int)i0f, j0 = (int)j0f;
        const int mi0 = refl(i0), mi1 = refl(i0 + 1);
        const int mj0 = refl(j0), mj1 = refl(j0 + 1);
        const int ilo = min(mi0, mi1), jlo = min(mj0, mj1);
        const bool sr = mi0 > mi1, sc = mj0 > mj1;   // |mi0-mi1| == |mj0-mj1| == 1 always
        const float* srcb = img + b * (IMW * IMW);

        // vertical blur at rows {ilo, ilo+1} over the 12-col union window, fully in registers
        float v0[12], v1[12];
        int R[12];
#pragma unroll
        for (int a = 0; a < 12; ++a) R[a] = refl(ilo - 5 + a) * IMW;
#pragma unroll
        for (int c = 0; c < 12; ++c) {
            const int cc = refl(jlo - 5 + c);
            const float* col = srcb + cc;
            float lo = 0.f, hi = 0.f;
#pragma unroll
            for (int a = 0; a < 12; ++a) {
                const float pv = col[R[a]];
                if (a < 11) lo = fmaf(KW[a], pv, lo);
                if (a > 0) hi = fmaf(KW[a - 1], pv, hi);
            }
            v0[c] = sr ? hi : lo;   // V(mi0, col)
            v1[c] = sr ? lo : hi;   // V(mi1, col)
        }
        // horizontal blur at cols {jlo, jlo+1}
        float y00lo = 0.f, y00hi = 0.f, y10lo = 0.f, y10hi = 0.f;
#pragma unroll
        for (int c = 0; c < 11; ++c) {
            y00lo = fmaf(KW[c], v0[c], y00lo);
            y00hi = fmaf(KW[c], v0[c + 1], y00hi);
            y10lo = fmaf(KW[c], v1[c], y10lo);
            y10hi = fmaf(KW[c], v1[c + 1], y10hi);
        }
        const float y00 = sc ? y00hi : y00lo;
        const float y01 = sc ? y00lo : y00hi;
        const float y10 = sc ? y10hi : y10lo;
        local = 0.5f * ((1.f - wi) * y00 + wi * y10 + (1.f - wj) * y00 + wj * y01);
        acc_idx = 1;
    } else {
        // ---- dist push: 256 i-points (registers) x 256 j-points (LDS tile) ----
        const int d = bx - GATHER_BLOCKS;
        const int b = d >> 8, ib = (d >> 4) & 15, jc = d & 15;
        const float2* tb = (const float2*)(trace + b * NP * 2);
        const float2 pi = tb[ib * 256 + tid];
        pj[tid] = tb[jc * 256 + tid];
        __syncthreads();
        float s = 0.f;
#pragma unroll 8
        for (int j = 0; j < 256; ++j) {
            const float dx = pi.x - pj[j].x;
            const float dy = pi.y - pj[j].y;
            const float d2 = fmaf(dx, dx, dy * dy);
            // sum of min(d, 0.05) over ALL ordered pairs (self adds 0); folded analytically in finalize
            s += fminf(__builtin_amdgcn_sqrtf(d2), 0.05f);
        }
        local = s;
        acc_idx = 0;
    }

    // ---- common block reduction + finalize ----
    for (int o = 32; o; o >>= 1) local += __shfl_down(local, o, 64);
    if ((tid & 63) == 0) red[tid >> 6] = local;
    __syncthreads();
    if (tid == 0) {
        atomicAdd(&accs[acc_idx], red[0] + red[1] + red[2] + red[3]);
        __threadfence();
        const unsigned o = atomicAdd(cnt, 1u);
        if (o == TOTAL_BLOCKS - 1) {   // last block: finalize
            __threadfence();
            const double M = (double)atomicAdd(&accs[0], 0.f);   // sum of min(d,0.05), ordered pairs
            const double S1 = (double)atomicAdd(&accs[1], 0.f);  // sum of intensities
            // sum over upper pairs of (0.05 - min(d,0.05)) = (0.05*8*(4096^2-4096) - M)/2
            const double dp = (6709248.0 - M) / 134184960.0;     // / (2 * 8 * npairs)
            const double il = 255.0 - S1 / 32768.0;
            out[0] = (float)(dp + il);
        }
    }
}

extern "C" void kernel_launch(void* const* d_in, const int* in_sizes, int n_in,
                              void* d_out, int out_size, void* d_ws, size_t ws_size,
                              hipStream_t stream) {
    const float* trace = (const float*)d_in[0];
    const float* img = (const float*)d_in[1];
    float* accs = (float*)d_ws;
    unsigned* cnt = (unsigned*)((char*)d_ws + 8);
    float* out = (float*)d_out;

    hipMemsetAsync(d_ws, 0, 64, stream);
    fused_loss<<<TOTAL_BLOCKS, 256, 0, stream>>>(trace, img, accs, cnt, out);
}

// Round 4
// 106.583 us; speedup vs baseline: 1.5645x; 1.5645x over previous
//
#include <hip/hip_runtime.h>

#define IMW 512
#define NP 4096

#define GATHER_BLOCKS 128
#define DIST_BLOCKS 1024               // 8 batches x 16 i-blocks x 8 j-chunks (256 i x 512 j tiles)
#define TOTAL_BLOCKS (GATHER_BLOCKS + DIST_BLOCKS)

// Gaussian kernel, sigma = 0.3*((11-1)*0.5 - 1) + 0.8 = 2.0, normalized (f64-accurate, rounded to f32)
__device__ constexpr float KW[11] = {
    0.00881223f, 0.02714359f, 0.06511407f, 0.12164908f, 0.17699836f,
    0.20056542f, 0.17699836f, 0.12164908f, 0.06511407f, 0.02714359f, 0.00881223f};

// reflect map: valid for r in [-5, 517]; matches both the blur pad and the intensity pad (512->510, 513->509)
__device__ __forceinline__ int refl(int r) {
    r = r < 0 ? -r : r;
    return r > 511 ? 1022 - r : r;
}

// Fused compute. blocks [0,128): intensity gather w/ inline 2D blur; blocks [128,1152): dist tiles.
// Each block writes ONE float partial to partials[bx] with a plain store — no atomics, no fences.
__global__ __launch_bounds__(256)
void fused_compute(const float* __restrict__ trace, const float* __restrict__ img,
                   float* __restrict__ partials) {
    const int tid = threadIdx.x;
    const int bx = blockIdx.x;
    __shared__ float2 pj[512];
    __shared__ float red[4];
    float local;

    if (bx < GATHER_BLOCKS) {
        // ---- intensity gather (+ full 2D separable blur inline from raw img) ----
        const int b = bx >> 4;
        const int p = (bx & 15) * 256 + tid;
        const float2 t2 = ((const float2*)trace)[b * NP + p];
        const float idx0 = t2.x * 512.f, idx1 = t2.y * 512.f;
        const float i0f = floorf(idx0 + 0.5f), j0f = floorf(idx1 + 0.5f);
        const float wi = idx0 - i0f, wj = idx1 - j0f;
        const int i0 = (int)i0f, j0 = (int)j0f;
        const int mi0 = refl(i0), mi1 = refl(i0 + 1);
        const int mj0 = refl(j0), mj1 = refl(j0 + 1);
        const int ilo = min(mi0, mi1), jlo = min(mj0, mj1);
        const bool sr = mi0 > mi1, sc = mj0 > mj1;   // |mi0-mi1| == |mj0-mj1| == 1 always
        const float* srcb = img + b * (IMW * IMW);

        float v0[12], v1[12];
        int R[12];
#pragma unroll
        for (int a = 0; a < 12; ++a) R[a] = refl(ilo - 5 + a) * IMW;
#pragma unroll
        for (int c = 0; c < 12; ++c) {
            const int cc = refl(jlo - 5 + c);
            const float* col = srcb + cc;
            float lo = 0.f, hi = 0.f;
#pragma unroll
            for (int a = 0; a < 12; ++a) {
                const float pv = col[R[a]];
                if (a < 11) lo = fmaf(KW[a], pv, lo);
                if (a > 0) hi = fmaf(KW[a - 1], pv, hi);
            }
            v0[c] = sr ? hi : lo;   // V(mi0, col)
            v1[c] = sr ? lo : hi;   // V(mi1, col)
        }
        float y00lo = 0.f, y00hi = 0.f, y10lo = 0.f, y10hi = 0.f;
#pragma unroll
        for (int c = 0; c < 11; ++c) {
            y00lo = fmaf(KW[c], v0[c], y00lo);
            y00hi = fmaf(KW[c], v0[c + 1], y00hi);
            y10lo = fmaf(KW[c], v1[c], y10lo);
            y10hi = fmaf(KW[c], v1[c + 1], y10hi);
        }
        const float y00 = sc ? y00hi : y00lo;
        const float y01 = sc ? y00lo : y00hi;
        const float y10 = sc ? y10hi : y10lo;
        local = 0.5f * ((1.f - wi) * y00 + wi * y10 + (1.f - wj) * y00 + wj * y01);
    } else {
        // ---- dist push: 256 i-points (registers) x 512 j-points (LDS tile) ----
        const int d = bx - GATHER_BLOCKS;
        const int b = d >> 7, ib = (d >> 3) & 15, jc = d & 7;
        const float2* tb = (const float2*)(trace + b * NP * 2);
        const float2 pi = tb[ib * 256 + tid];
        pj[tid] = tb[jc * 512 + tid];
        pj[tid + 256] = tb[jc * 512 + tid + 256];
        __syncthreads();
        float s = 0.f;
#pragma unroll 8
        for (int j = 0; j < 512; ++j) {
            const float dx = pi.x - pj[j].x;
            const float dy = pi.y - pj[j].y;
            const float d2 = fmaf(dx, dx, dy * dy);
            // sum of min(d, 0.05) over ALL ordered pairs (self adds 0); folded analytically in finalize
            s += fminf(__builtin_amdgcn_sqrtf(d2), 0.05f);
        }
        local = s;
    }

    // ---- block reduction, plain store of this block's partial ----
    for (int o = 32; o; o >>= 1) local += __shfl_down(local, o, 64);
    if ((tid & 63) == 0) red[tid >> 6] = local;
    __syncthreads();
    if (tid == 0) partials[bx] = red[0] + red[1] + red[2] + red[3];
}

// Finalize: one block sums the 1152 partials (slots [0,128)=gather, [128,1152)=dist) -> scalar loss.
__global__ __launch_bounds__(256)
void finalize(const float* __restrict__ partials, float* __restrict__ out) {
    const int tid = threadIdx.x;
    float sg = 0.f, sd = 0.f;
    for (int i = tid; i < TOTAL_BLOCKS; i += 256) {
        const float v = partials[i];
        if (i < GATHER_BLOCKS) sg += v; else sd += v;
    }
    for (int o = 32; o; o >>= 1) {
        sg += __shfl_down(sg, o, 64);
        sd += __shfl_down(sd, o, 64);
    }
    __shared__ float rg[4], rd[4];
    if ((tid & 63) == 0) { rg[tid >> 6] = sg; rd[tid >> 6] = sd; }
    __syncthreads();
    if (tid == 0) {
        const double M  = (double)(rd[0] + rd[1] + rd[2] + rd[3]);  // sum min(d,0.05), ordered pairs
        const double S1 = (double)(rg[0] + rg[1] + rg[2] + rg[3]);  // sum of intensities
        // upper-pair sum of (0.05 - min(d,0.05)) = (0.05*8*(4096^2-4096) - M)/2; / (8*npairs)
        const double dp = (6709248.0 - M) / 134184960.0;
        const double il = 255.0 - S1 / 32768.0;
        out[0] = (float)(dp + il);
    }
}

extern "C" void kernel_launch(void* const* d_in, const int* in_sizes, int n_in,
                              void* d_out, int out_size, void* d_ws, size_t ws_size,
                              hipStream_t stream) {
    const float* trace = (const float*)d_in[0];
    const float* img = (const float*)d_in[1];
    float* partials = (float*)d_ws;
    float* out = (float*)d_out;

    fused_compute<<<TOTAL_BLOCKS, 256, 0, stream>>>(trace, img, partials);
    finalize<<<1, 256, 0, stream>>>(partials, out);
}